// Round 3
// baseline (557.537 us; speedup 1.0000x reference)
//
#include <hip/hip_runtime.h>

#define BS 4
#define SL 2048
#define NE 1024
#define NH 16
#define HD 64
#define N3 3072

typedef __attribute__((ext_vector_type(8))) __bf16 bf16x8;
typedef __attribute__((ext_vector_type(4))) float f32x4;
typedef unsigned short u16;

static_assert(sizeof(bf16x8) == 16, "bf16x8 must be 16B");

__device__ __forceinline__ u16 f2bf(float f) {
  union { float f; unsigned int u; } v; v.f = f;
  unsigned int r = v.u + 0x7FFFu + ((v.u >> 16) & 1u);
  return (u16)(r >> 16);
}
__device__ __forceinline__ float bf2f(u16 h) {
  union { unsigned int u; float f; } v; v.u = ((unsigned int)h) << 16;
  return v.f;
}

// ---------------- dtype sniffer ----------------
// If x is bf16: bits[14:7] of each 32b word = exponent of the low bf16
// element -> in [118,130] for ~all N(0,1) samples. If x is fp32: those are
// mantissa bits -> ~uniform, ~5% hit rate. flag=1 means "inputs are bf16".
__global__ void detect_dtype(const unsigned int* __restrict__ x,
                             int* __restrict__ flag) {
  int lane = threadIdx.x;  // 64 threads
  unsigned int w = x[lane];
  int e = (w >> 7) & 0xFF;
  bool hit = (e >= 118 && e <= 130);
  unsigned long long m = __ballot(hit);
  if (lane == 0) *flag = (__popcll(m) >= 32) ? 1 : 0;
}

// ---------------- W transpose+convert: Wt[n*K+k] = bf16(W[k*N+n]) ----------
__global__ void transpose_w(const void* __restrict__ W, u16* __restrict__ Wt,
                            int K, int N, const int* __restrict__ flagp) {
  __shared__ u16 tile[32][33];
  const int isbf = *flagp;
  int bn = blockIdx.x * 32, bk = blockIdx.y * 32;
  int tx = threadIdx.x, ty = threadIdx.y;  // blockDim = (32, 8)
  if (isbf) {
    const u16* Wh = (const u16*)W;
    for (int r = 0; r < 32; r += 8)
      tile[ty + r][tx] = Wh[(size_t)(bk + ty + r) * N + bn + tx];
  } else {
    const float* Wf = (const float*)W;
    for (int r = 0; r < 32; r += 8)
      tile[ty + r][tx] = f2bf(Wf[(size_t)(bk + ty + r) * N + bn + tx]);
  }
  __syncthreads();
  for (int r = 0; r < 32; r += 8)
    Wt[(size_t)(bn + ty + r) * K + bk + tx] = tile[tx][ty + r];
}

// ---------------- GEMM: C[M,N] = A[M,K] @ Bt[N,K]^T + bias[N] ---------------
// A: bf16 (or fp32 if a_flagged && flag==fp32), row stride lda.
// Bt: bf16 [N,K]. bias: raw input (dtype per flag). C: bf16, or fp32 when
// c_flagged && flag==fp32. 128x128x32 tile, 4 waves, 4x4 mfma 16x16x32.
#define LDSR 40  // LDS row stride: 32 + 8 pad elems, rows stay 16B aligned

__global__ __launch_bounds__(256)
void gemm_bt_bias(const void* __restrict__ A, const u16* __restrict__ Bt,
                  const void* __restrict__ bias, void* __restrict__ C,
                  int M, int N, int K, int lda,
                  const int* __restrict__ flagp, int a_flagged, int c_flagged) {
  __shared__ u16 As[128 * LDSR];
  __shared__ u16 Bs[128 * LDSR];

  const int isbf = *flagp;
  const bool a32 = a_flagged && !isbf;
  const bool c32 = c_flagged && !isbf;

  const int tid = threadIdx.x;
  const int wave = tid >> 6, lane = tid & 63;
  const int lq = lane >> 4, lr = lane & 15;
  const int m0 = blockIdx.y * 128, n0 = blockIdx.x * 128;
  const int wm = (wave & 1) * 64, wn = (wave >> 1) * 64;

  const f32x4 fzero = {0.f, 0.f, 0.f, 0.f};
  f32x4 acc[4][4];
#pragma unroll
  for (int i = 0; i < 4; i++)
#pragma unroll
    for (int j = 0; j < 4; j++) acc[i][j] = fzero;

  for (int k0 = 0; k0 < K; k0 += 32) {
    __syncthreads();  // previous iteration's LDS readers are done
#pragma unroll
    for (int c = tid; c < 512; c += 256) {
      int row = c >> 2, ko = (c & 3) * 8;
      if (a32) {
        const float* src = (const float*)A + (size_t)(m0 + row) * lda + k0 + ko;
        float4 f0 = *(const float4*)src;
        float4 f1 = *(const float4*)(src + 4);
        union { int4 v; u16 h[8]; } p;
        p.h[0] = f2bf(f0.x); p.h[1] = f2bf(f0.y);
        p.h[2] = f2bf(f0.z); p.h[3] = f2bf(f0.w);
        p.h[4] = f2bf(f1.x); p.h[5] = f2bf(f1.y);
        p.h[6] = f2bf(f1.z); p.h[7] = f2bf(f1.w);
        *(int4*)&As[row * LDSR + ko] = p.v;
      } else {
        *(int4*)&As[row * LDSR + ko] =
            *(const int4*)((const u16*)A + (size_t)(m0 + row) * lda + k0 + ko);
      }
      *(int4*)&Bs[row * LDSR + ko] =
          *(const int4*)&Bt[(size_t)(n0 + row) * K + k0 + ko];
    }
    __syncthreads();

    bf16x8 af[4], bfr[4];
#pragma unroll
    for (int i = 0; i < 4; i++)
      af[i] = *(const bf16x8*)&As[(wm + i * 16 + lr) * LDSR + lq * 8];
#pragma unroll
    for (int j = 0; j < 4; j++)
      bfr[j] = *(const bf16x8*)&Bs[(wn + j * 16 + lr) * LDSR + lq * 8];
#pragma unroll
    for (int i = 0; i < 4; i++)
#pragma unroll
      for (int j = 0; j < 4; j++)
        acc[i][j] = __builtin_amdgcn_mfma_f32_16x16x32_bf16(af[i], bfr[j],
                                                            acc[i][j], 0, 0, 0);
  }

  // Epilogue. C/D layout: col = lane&15, row = (lane>>4)*4 + reg.
#pragma unroll
  for (int j = 0; j < 4; j++) {
    int col = n0 + wn + j * 16 + lr;
    float bv = isbf ? bf2f(((const u16*)bias)[col]) : ((const float*)bias)[col];
#pragma unroll
    for (int i = 0; i < 4; i++) {
#pragma unroll
      for (int r = 0; r < 4; r++) {
        int row = m0 + wm + i * 16 + lq * 4 + r;
        float val = acc[i][j][r] + bv;
        if (c32) ((float*)C)[(size_t)row * N + col] = val;
        else     ((u16*)C)[(size_t)row * N + col]   = f2bf(val);
      }
    }
  }
}

// ---------------- Flash attention (causal), Y written in-place over Q ------
// qkv: [b][s][3072], Q at +0, K at +1024, V at +2048, head h at h*64.
// Block = 4 waves, 64 queries (16/wave), 64-key LDS tiles. Each block reads
// only its own Q rows/head-slice (into registers, at start) and later writes
// Y to exactly those addresses — no cross-block overlap, in-place is safe.
#define KSTR 72  // 64 + 8 pad elems (rows stay 16B aligned)

__global__ __launch_bounds__(256)
void attn_kernel(u16* __restrict__ qkv) {
  __shared__ u16 Ks[64 * KSTR];
  __shared__ u16 Vt[64 * KSTR];
  __shared__ u16 Ps[4 * 16 * KSTR];

  const int tid = threadIdx.x;
  const int w = tid >> 6, lane = tid & 63;
  const int lq = lane >> 4, lr = lane & 15;
  const int qb = blockIdx.x, h = blockIdx.y, b = blockIdx.z;
  const int q0w = qb * 64 + w * 16;

  u16* base = qkv + (size_t)b * SL * N3;

  // Q fragments (A-layout: m=lane&15, k=(lane>>4)*8+j), d = 0..63
  bf16x8 qf0, qf1;
  {
    const u16* qrow = base + (size_t)(q0w + lr) * N3 + h * HD;
    qf0 = *(const bf16x8*)(qrow + lq * 8);
    qf1 = *(const bf16x8*)(qrow + 32 + lq * 8);
  }

  const f32x4 fzero = {0.f, 0.f, 0.f, 0.f};
  f32x4 o[4];
#pragma unroll
  for (int j = 0; j < 4; j++) o[j] = fzero;
  float mrow[4], lrow[4];
#pragma unroll
  for (int r = 0; r < 4; r++) { mrow[r] = -1e30f; lrow[r] = 0.f; }

  const int ntiles = qb + 1;
  for (int kt = 0; kt < ntiles; kt++) {
    const int key0 = kt * 64;
    __syncthreads();
    for (int c = tid; c < 512; c += 256) {
      int key = c & 63, doff = (c >> 6) * 8;
      const u16* krow = base + (size_t)(key0 + key) * N3 + NE + h * HD;
      *(int4*)&Ks[key * KSTR + doff] = *(const int4*)(krow + doff);
      const u16* vrow = base + (size_t)(key0 + key) * N3 + 2 * NE + h * HD;
      union { int4 v; u16 u[8]; } tmp;
      tmp.v = *(const int4*)(vrow + doff);
#pragma unroll
      for (int j = 0; j < 8; j++) Vt[(doff + j) * KSTR + key] = tmp.u[j];
    }
    __syncthreads();

    f32x4 s[4];
#pragma unroll
    for (int j = 0; j < 4; j++) {
      bf16x8 kf0 = *(const bf16x8*)&Ks[(j * 16 + lr) * KSTR + lq * 8];
      bf16x8 kf1 = *(const bf16x8*)&Ks[(j * 16 + lr) * KSTR + 32 + lq * 8];
      f32x4 z = fzero;
      z = __builtin_amdgcn_mfma_f32_16x16x32_bf16(qf0, kf0, z, 0, 0, 0);
      s[j] = __builtin_amdgcn_mfma_f32_16x16x32_bf16(qf1, kf1, z, 0, 0, 0);
    }

    // scale + causal mask (S C-layout: col=key0+j*16+lr, row=q0w+lq*4+r)
#pragma unroll
    for (int j = 0; j < 4; j++) {
      int col = key0 + j * 16 + lr;
#pragma unroll
      for (int r = 0; r < 4; r++) {
        float sv = s[j][r] * 0.125f;
        s[j][r] = (col > q0w + lq * 4 + r) ? -1e30f : sv;
      }
    }

    // online softmax (per C-row, reduced across 16 contiguous col-lanes)
    float mnew[4], alpha[4];
#pragma unroll
    for (int r = 0; r < 4; r++) {
      float mt = fmaxf(fmaxf(s[0][r], s[1][r]), fmaxf(s[2][r], s[3][r]));
#pragma unroll
      for (int off = 1; off < 16; off <<= 1)
        mt = fmaxf(mt, __shfl_xor(mt, off, 16));
      mnew[r] = fmaxf(mrow[r], mt);
      alpha[r] = __expf(mrow[r] - mnew[r]);
      mrow[r] = mnew[r];
    }
    float psum[4] = {0.f, 0.f, 0.f, 0.f};
#pragma unroll
    for (int j = 0; j < 4; j++)
#pragma unroll
      for (int r = 0; r < 4; r++) {
        float p = __expf(s[j][r] - mnew[r]);
        s[j][r] = p;
        psum[r] += p;
      }
#pragma unroll
    for (int r = 0; r < 4; r++) {
      float ps = psum[r];
#pragma unroll
      for (int off = 1; off < 16; off <<= 1) ps += __shfl_xor(ps, off, 16);
      lrow[r] = lrow[r] * alpha[r] + ps;
#pragma unroll
      for (int j = 0; j < 4; j++) o[j][r] *= alpha[r];
    }

    // P: C-layout regs -> LDS -> A-layout frags (per-wave private region)
    u16* myP = &Ps[w * 16 * KSTR];
#pragma unroll
    for (int j = 0; j < 4; j++)
#pragma unroll
      for (int r = 0; r < 4; r++)
        myP[(lq * 4 + r) * KSTR + j * 16 + lr] = f2bf(s[j][r]);

    __syncthreads();  // fence the u16 stores vs the bf16x8 reads below

    bf16x8 pf0 = *(const bf16x8*)&myP[lr * KSTR + lq * 8];
    bf16x8 pf1 = *(const bf16x8*)&myP[lr * KSTR + 32 + lq * 8];
#pragma unroll
    for (int jd = 0; jd < 4; jd++) {
      bf16x8 vf0 = *(const bf16x8*)&Vt[(jd * 16 + lr) * KSTR + lq * 8];
      bf16x8 vf1 = *(const bf16x8*)&Vt[(jd * 16 + lr) * KSTR + 32 + lq * 8];
      o[jd] = __builtin_amdgcn_mfma_f32_16x16x32_bf16(pf0, vf0, o[jd], 0, 0, 0);
      o[jd] = __builtin_amdgcn_mfma_f32_16x16x32_bf16(pf1, vf1, o[jd], 0, 0, 0);
    }
  }

  // epilogue: O /= l, write Y over the Q slot: qkv[b][s][h*64+d]
#pragma unroll
  for (int r = 0; r < 4; r++) {
    float inv = 1.0f / lrow[r];
    int srow = q0w + lq * 4 + r;
    u16* yrow = base + (size_t)srow * N3 + h * HD;
#pragma unroll
    for (int j = 0; j < 4; j++) yrow[j * 16 + lr] = f2bf(o[j][r] * inv);
  }
}

// ---------------- host launch ----------------
extern "C" void kernel_launch(void* const* d_in, const int* in_sizes, int n_in,
                              void* d_out, int out_size, void* d_ws,
                              size_t ws_size, hipStream_t stream) {
  // d_in: x, mask(int32, ignored - causal), Wqkv, bqkv, Wo, bo
  int* flag   = (int*)d_ws;
  u16* qkvbuf = (u16*)((char*)d_ws + 256);            // BS*SL*3072 bf16
  u16* WqkvT  = qkvbuf + (size_t)BS * SL * N3;        // [3072,1024] bf16
  u16* WoT    = WqkvT + (size_t)N3 * NE;              // [1024,1024] bf16

  detect_dtype<<<1, 64, 0, stream>>>((const unsigned int*)d_in[0], flag);
  transpose_w<<<dim3(N3 / 32, NE / 32), dim3(32, 8), 0, stream>>>(
      d_in[2], WqkvT, NE, N3, flag);
  transpose_w<<<dim3(NE / 32, NE / 32), dim3(32, 8), 0, stream>>>(
      d_in[4], WoT, NE, NE, flag);
  gemm_bt_bias<<<dim3(N3 / 128, (BS * SL) / 128), 256, 0, stream>>>(
      d_in[0], WqkvT, d_in[3], qkvbuf, BS * SL, N3, NE, NE, flag,
      /*a_flagged=*/1, /*c_flagged=*/0);
  attn_kernel<<<dim3(SL / 64, NH, BS), 256, 0, stream>>>(qkvbuf);
  gemm_bt_bias<<<dim3(NE / 128, (BS * SL) / 128), 256, 0, stream>>>(
      qkvbuf, WoT, d_in[5], d_out, BS * SL, NE, NE, N3, flag,
      /*a_flagged=*/0, /*c_flagged=*/1);
}

// Round 4
// 410.396 us; speedup vs baseline: 1.3585x; 1.3585x over previous
//
#include <hip/hip_runtime.h>

#define BS 4
#define SL 2048
#define NE 1024
#define NH 16
#define HD 64
#define N3 3072

typedef __attribute__((ext_vector_type(8))) __bf16 bf16x8;
typedef __attribute__((ext_vector_type(4))) float f32x4;
typedef unsigned short u16;

__device__ __forceinline__ u16 f2bf(float f) {
  union { float f; unsigned int u; } v; v.f = f;
  unsigned int r = v.u + 0x7FFFu + ((v.u >> 16) & 1u);
  return (u16)(r >> 16);
}
__device__ __forceinline__ u16 f2bf_rtz(float f) {
  union { float f; unsigned int u; } v; v.f = f;
  return (u16)(v.u >> 16);
}

// global -> LDS direct 16B copy. LDS dest is WAVE-UNIFORM base; HW adds
// lane*16. Global address is per-lane.
__device__ __forceinline__ void gld16(const void* g, void* l) {
#if __has_builtin(__builtin_amdgcn_global_load_lds)
  __builtin_amdgcn_global_load_lds(
      (const __attribute__((address_space(1))) unsigned int*)g,
      (__attribute__((address_space(3))) unsigned int*)l, 16, 0, 0);
#else
  *(int4*)((char*)l + (size_t)(threadIdx.x & 63) * 16) = *(const int4*)g;
#endif
}

// ---------------- W transpose+convert: Wt[n*K+k] = bf16(W[k*N+n]) ----------
__global__ void transpose_w(const float* __restrict__ W, u16* __restrict__ Wt,
                            int K, int N) {
  __shared__ u16 tile[32][33];
  int bn = blockIdx.x * 32, bk = blockIdx.y * 32;
  int tx = threadIdx.x, ty = threadIdx.y;  // blockDim = (32, 8)
  for (int r = 0; r < 32; r += 8)
    tile[ty + r][tx] = f2bf(W[(size_t)(bk + ty + r) * N + bn + tx]);
  __syncthreads();
  for (int r = 0; r < 32; r += 8)
    Wt[(size_t)(bn + ty + r) * K + bk + tx] = tile[tx][ty + r];
}

// ---------------- GEMM: C[M,N] = A[M,K] @ Bt[N,K]^T + bias[N] ---------------
// A32: A is fp32 (convert in staging, padded LDS). Else A bf16 via
// global_load_lds (unpadded). C32: store fp32, else bf16.
template <int A32, int C32>
__global__ __launch_bounds__(256) void gemm_bt(
    const void* __restrict__ A, const u16* __restrict__ Bt,
    const float* __restrict__ bias, void* __restrict__ C, int M, int N, int K,
    int lda) {
  constexpr int AST = A32 ? 40 : 32;  // As row stride (elems)
  __shared__ u16 As[128 * AST];
  __shared__ u16 Bs[128 * 32];

  const int tid = threadIdx.x;
  const int wave = tid >> 6, lane = tid & 63;
  const int lq = lane >> 4, lr = lane & 15;
  const int m0 = blockIdx.y * 128, n0 = blockIdx.x * 128;
  const int wm = (wave & 1) * 64, wn = (wave >> 1) * 64;

  const f32x4 fzero = {0.f, 0.f, 0.f, 0.f};
  f32x4 acc[4][4];
#pragma unroll
  for (int i = 0; i < 4; i++)
#pragma unroll
    for (int j = 0; j < 4; j++) acc[i][j] = fzero;

  for (int k0 = 0; k0 < K; k0 += 32) {
    __syncthreads();  // previous iteration's LDS readers are done
    if (A32) {
#pragma unroll
      for (int c = tid; c < 512; c += 256) {
        int row = c >> 2, ko = (c & 3) * 8;
        const float* src = (const float*)A + (size_t)(m0 + row) * lda + k0 + ko;
        float4 f0 = *(const float4*)src;
        float4 f1 = *(const float4*)(src + 4);
        union { int4 v; u16 h[8]; } p;
        p.h[0] = f2bf(f0.x); p.h[1] = f2bf(f0.y);
        p.h[2] = f2bf(f0.z); p.h[3] = f2bf(f0.w);
        p.h[4] = f2bf(f1.x); p.h[5] = f2bf(f1.y);
        p.h[6] = f2bf(f1.z); p.h[7] = f2bf(f1.w);
        *(int4*)&As[row * AST + ko] = p.v;
      }
    } else {
#pragma unroll
      for (int t = 0; t < 2; t++) {
        int chunk = wave * 2 + t;  // 1 KB chunk = 16 rows x 64 B
        const u16* g = (const u16*)A +
                       (size_t)(m0 + chunk * 16 + (lane >> 2)) * lda + k0 +
                       (lane & 3) * 8;
        gld16(g, &As[chunk * 512]);
      }
    }
#pragma unroll
    for (int t = 0; t < 2; t++) {
      int chunk = wave * 2 + t;
      const u16* g = Bt + (size_t)(n0 + chunk * 16 + (lane >> 2)) * K + k0 +
                     (lane & 3) * 8;
      gld16(g, &Bs[chunk * 512]);
    }
    __syncthreads();  // drains vmcnt (global_load_lds) + lgkm

    bf16x8 af[4], bfr[4];
#pragma unroll
    for (int i = 0; i < 4; i++)
      af[i] = *(const bf16x8*)&As[(wm + i * 16 + lr) * AST + lq * 8];
#pragma unroll
    for (int j = 0; j < 4; j++)
      bfr[j] = *(const bf16x8*)&Bs[(wn + j * 16 + lr) * 32 + lq * 8];
#pragma unroll
    for (int i = 0; i < 4; i++)
#pragma unroll
      for (int j = 0; j < 4; j++)
        acc[i][j] = __builtin_amdgcn_mfma_f32_16x16x32_bf16(af[i], bfr[j],
                                                            acc[i][j], 0, 0, 0);
  }

  // Epilogue. C/D layout: col = lane&15, row = (lane>>4)*4 + reg.
#pragma unroll
  for (int j = 0; j < 4; j++) {
    int col = n0 + wn + j * 16 + lr;
    float bv = bias[col];
#pragma unroll
    for (int i = 0; i < 4; i++) {
#pragma unroll
      for (int r = 0; r < 4; r++) {
        int row = m0 + wm + i * 16 + lq * 4 + r;
        float val = acc[i][j][r] + bv;
        if (C32) ((float*)C)[(size_t)row * N + col] = val;
        else     ((u16*)C)[(size_t)row * N + col]   = f2bf(val);
      }
    }
  }
}

// ---------------- Flash attention (causal), paired q-tiles ----------------
// Block p handles q-tiles {p, 31-p} sharing K/V staging -> every block does
// exactly 33 tile-halves (perfect load balance). Y written over the Q slot.
#define KSTR 72  // 64 + 8 pad elems

__device__ __forceinline__ void attn_step(
    const bf16x8& q0, const bf16x8& q1, const u16* __restrict__ Ks,
    const u16* __restrict__ Vs, u16* __restrict__ myP, bool diag, int w,
    int lq, int lr, f32x4 (&o)[4], float (&m_)[4], float (&l_)[4]) {
  const f32x4 fzero = {0.f, 0.f, 0.f, 0.f};
  f32x4 s[4];
#pragma unroll
  for (int j = 0; j < 4; j++) {
    bf16x8 kf0 = *(const bf16x8*)&Ks[(j * 16 + lr) * KSTR + lq * 8];
    bf16x8 kf1 = *(const bf16x8*)&Ks[(j * 16 + lr) * KSTR + 32 + lq * 8];
    f32x4 z = fzero;
    z = __builtin_amdgcn_mfma_f32_16x16x32_bf16(q0, kf0, z, 0, 0, 0);
    s[j] = __builtin_amdgcn_mfma_f32_16x16x32_bf16(q1, kf1, z, 0, 0, 0);
  }
#pragma unroll
  for (int j = 0; j < 4; j++)
#pragma unroll
    for (int r = 0; r < 4; r++) s[j][r] *= 0.125f;
  if (diag) {
    // within diagonal tile: col (local) = j*16+lr, row (local) = w*16+lq*4+r
#pragma unroll
    for (int j = 0; j < 4; j++)
#pragma unroll
      for (int r = 0; r < 4; r++)
        if (j * 16 + lr > w * 16 + lq * 4 + r) s[j][r] = -1e30f;
  }
  float alpha[4];
#pragma unroll
  for (int r = 0; r < 4; r++) {
    float mt = fmaxf(fmaxf(s[0][r], s[1][r]), fmaxf(s[2][r], s[3][r]));
#pragma unroll
    for (int off = 1; off < 16; off <<= 1)
      mt = fmaxf(mt, __shfl_xor(mt, off, 16));
    float mn = fmaxf(m_[r], mt);
    alpha[r] = __expf(m_[r] - mn);
    m_[r] = mn;
  }
  float psum[4] = {0.f, 0.f, 0.f, 0.f};
#pragma unroll
  for (int j = 0; j < 4; j++)
#pragma unroll
    for (int r = 0; r < 4; r++) {
      float p = __expf(s[j][r] - m_[r]);
      s[j][r] = p;
      psum[r] += p;
    }
#pragma unroll
  for (int r = 0; r < 4; r++) {
    l_[r] = l_[r] * alpha[r] + psum[r];  // per-lane partial; reduce at end
#pragma unroll
    for (int j = 0; j < 4; j++) o[j][r] *= alpha[r];
  }
  // P: C-layout regs -> LDS (wave-private) -> A-layout frags
#pragma unroll
  for (int j = 0; j < 4; j++)
#pragma unroll
    for (int r = 0; r < 4; r++)
      myP[(lq * 4 + r) * KSTR + j * 16 + lr] = f2bf_rtz(s[j][r]);
  __asm__ volatile("s_waitcnt lgkmcnt(0)" ::: "memory");  // wave-level fence
  bf16x8 pf0 = *(const bf16x8*)&myP[lr * KSTR + lq * 8];
  bf16x8 pf1 = *(const bf16x8*)&myP[lr * KSTR + 32 + lq * 8];
#pragma unroll
  for (int jd = 0; jd < 4; jd++) {
    bf16x8 vf0 = *(const bf16x8*)&Vs[(jd * 16 + lr) * KSTR + lq * 8];
    bf16x8 vf1 = *(const bf16x8*)&Vs[(jd * 16 + lr) * KSTR + 32 + lq * 8];
    o[jd] = __builtin_amdgcn_mfma_f32_16x16x32_bf16(pf0, vf0, o[jd], 0, 0, 0);
    o[jd] = __builtin_amdgcn_mfma_f32_16x16x32_bf16(pf1, vf1, o[jd], 0, 0, 0);
  }
}

__global__ __launch_bounds__(256, 4) void attn_paired(u16* __restrict__ qkv) {
  __shared__ u16 Ks[64 * KSTR];
  __shared__ u16 Vs[64 * KSTR];
  __shared__ u16 Ps[2][4][16 * KSTR];

  const int tid = threadIdx.x;
  const int w = tid >> 6, lane = tid & 63;
  const int lq = lane >> 4, lr = lane & 15;
  const int p = blockIdx.x, h = blockIdx.y, b = blockIdx.z;
  const int qt[2] = {p, (SL / 64 - 1) - p};  // lo, hi

  u16* base = qkv + (size_t)b * SL * N3;

  bf16x8 qf[2][2];
#pragma unroll
  for (int half = 0; half < 2; half++) {
    const u16* qrow = base + (size_t)(qt[half] * 64 + w * 16 + lr) * N3 + h * HD;
    qf[half][0] = *(const bf16x8*)(qrow + lq * 8);
    qf[half][1] = *(const bf16x8*)(qrow + 32 + lq * 8);
  }

  const f32x4 fzero = {0.f, 0.f, 0.f, 0.f};
  f32x4 o[2][4];
  float m_[2][4], l_[2][4];
#pragma unroll
  for (int half = 0; half < 2; half++)
#pragma unroll
    for (int r = 0; r < 4; r++) {
      o[half][r] = fzero;
      m_[half][r] = -1e30f;
      l_[half][r] = 0.f;
    }

  const int ktend = qt[1] + 1;
  for (int kt = 0; kt < ktend; kt++) {
    const int key0 = kt * 64;
    __syncthreads();
    for (int c = tid; c < 512; c += 256) {
      int key = c & 63, d0 = (c >> 6) * 8;
      const u16* krow = base + (size_t)(key0 + key) * N3 + NE + h * HD;
      *(int4*)&Ks[key * KSTR + d0] = *(const int4*)(krow + d0);
      const u16* vrow = base + (size_t)(key0 + key) * N3 + 2 * NE + h * HD;
      union { int4 v; u16 u[8]; } tmp;
      tmp.v = *(const int4*)(vrow + d0);
#pragma unroll
      for (int j = 0; j < 8; j++) Vs[(d0 + j) * KSTR + key] = tmp.u[j];
    }
    __syncthreads();

    attn_step(qf[1][0], qf[1][1], Ks, Vs, &Ps[1][w][0], kt == qt[1], w, lq, lr,
              o[1], m_[1], l_[1]);
    if (kt <= qt[0])
      attn_step(qf[0][0], qf[0][1], Ks, Vs, &Ps[0][w][0], kt == qt[0], w, lq,
                lr, o[0], m_[0], l_[0]);
  }

  // epilogue: reduce per-lane l partials across the 16 col-lanes, write Y
#pragma unroll
  for (int half = 0; half < 2; half++) {
#pragma unroll
    for (int r = 0; r < 4; r++) {
      float lsum = l_[half][r];
#pragma unroll
      for (int off = 1; off < 16; off <<= 1) lsum += __shfl_xor(lsum, off, 16);
      float inv = 1.0f / lsum;
      int srow = qt[half] * 64 + w * 16 + lq * 4 + r;
      u16* yrow = base + (size_t)srow * N3 + h * HD;
#pragma unroll
      for (int j = 0; j < 4; j++) yrow[j * 16 + lr] = f2bf(o[half][j][r] * inv);
    }
  }
}

// ---------------- host launch ----------------
extern "C" void kernel_launch(void* const* d_in, const int* in_sizes, int n_in,
                              void* d_out, int out_size, void* d_ws,
                              size_t ws_size, hipStream_t stream) {
  // inputs (fp32 / int32): x, mask(ignored - analytic causal), Wqkv, bqkv,
  // Wo, bo
  const float* x    = (const float*)d_in[0];
  const float* Wqkv = (const float*)d_in[2];
  const float* bqkv = (const float*)d_in[3];
  const float* Wo   = (const float*)d_in[4];
  const float* bo   = (const float*)d_in[5];

  u16* WqkvT  = (u16*)d_ws;                       // [3072,1024] bf16
  u16* WoT    = WqkvT + (size_t)N3 * NE;          // [1024,1024] bf16
  u16* qkvbuf = WoT + (size_t)NE * NE;            // [8192,3072] bf16

  transpose_w<<<dim3(N3 / 32, NE / 32), dim3(32, 8), 0, stream>>>(Wqkv, WqkvT,
                                                                  NE, N3);
  transpose_w<<<dim3(NE / 32, NE / 32), dim3(32, 8), 0, stream>>>(Wo, WoT, NE,
                                                                  NE);
  gemm_bt<1, 0><<<dim3(N3 / 128, (BS * SL) / 128), 256, 0, stream>>>(
      x, WqkvT, bqkv, qkvbuf, BS * SL, N3, NE, NE);
  attn_paired<<<dim3(SL / 128, NH, BS), 256, 0, stream>>>(qkvbuf);
  gemm_bt<0, 1><<<dim3(NE / 128, (BS * SL) / 128), 256, 0, stream>>>(
      qkvbuf, WoT, bo, d_out, BS * SL, NE, NE, N3);
}